// Round 10
// baseline (259.367 us; speedup 1.0000x reference)
//
#include <hip/hip_runtime.h>

#define NG    64
#define NPG   128
#define KNN   100
#define FIN   6
#define WID   128
#define D2    768
#define NEG   0.01f
#define INV101 (1.0f/101.0f)
#define BNEPS 1e-5f
#define BIG   1e30f

#define AGENT __HIP_MEMORY_SCOPE_AGENT

typedef float f4 __attribute__((ext_vector_type(4)));

__device__ __forceinline__ float leaky(float v) { return v > 0.f ? v : NEG * v; }

// barrier among `target` blocks on counter c (counter must be 0 before first use).
// agent-scope acq_rel/acquire => compiler emits L2 writeback on release, L2 inv on acquire.
__device__ __forceinline__ void gbar(unsigned* c, unsigned target) {
    __syncthreads();
    if (threadIdx.x == 0) {
        __hip_atomic_fetch_add(c, 1u, __ATOMIC_ACQ_REL, AGENT);
        while (__hip_atomic_load(c, __ATOMIC_ACQUIRE, AGENT) < target)
            __builtin_amdgcn_s_sleep(2);
    }
    __syncthreads();
}

// ---------------- K1: kNN + A = (I+M)/101, + lin_W LLC warm-read ----------------
// grid 512 (8 blocks/graph, 16 rows each), block 256
__global__ __launch_bounds__(256) void k_knn(const float* __restrict__ x, float* __restrict__ A,
                                             const float* __restrict__ linW)
{
    int g  = blockIdx.x >> 3;
    int i0 = (blockIdx.x & 7) * 16;
    __shared__ float xg[NPG * FIN];
    __shared__ float sq[NPG];
    __shared__ float D[16][NPG];
    const float* xp = x + g * NPG * FIN;
    for (int t = threadIdx.x; t < NPG * FIN; t += 256) xg[t] = xp[t];
    __syncthreads();
    if (threadIdx.x < NPG) {
        float s = 0.f;
        #pragma unroll
        for (int c = 0; c < FIN; ++c) { float v = xg[threadIdx.x * FIN + c]; s = fmaf(v, v, s); }
        sq[threadIdx.x] = s;
    }
    __syncthreads();
    for (int e = threadIdx.x; e < 16 * NPG; e += 256) {
        int il = e >> 7, j = e & 127;
        int i = i0 + il;
        float d;
        if (j == i) d = BIG;
        else {
            float dot = 0.f;
            #pragma unroll
            for (int c = 0; c < FIN; ++c) dot = fmaf(xg[i * FIN + c], xg[j * FIN + c], dot);
            d = sq[i] + sq[j] - 2.f * dot;
        }
        D[il][j] = d;
    }
    __syncthreads();
    float* Ag = A + (size_t)g * NPG * NPG;
    for (int e = threadIdx.x; e < 16 * NPG; e += 256) {
        int il = e >> 7, j = e & 127;
        int i = i0 + il;
        float aval;
        if (i == j) aval = INV101;
        else {
            float dj = D[il][j];
            int cnt = 0;
            #pragma unroll 8
            for (int k = 0; k < NPG; ++k) {
                float dk = D[il][k];
                cnt += (dk < dj || (dk == dj && k < j)) ? 1 : 0;
            }
            aval = (cnt < KNN) ? INV101 : 0.f;
        }
        Ag[i * NPG + j] = aval;
    }
    // ---- LLC warm-read of lin_W: 512 blocks x 1440 float4 = 5*768*768 floats exactly ----
    {
        const f4* w4 = (const f4*)linW;
        f4 s = {0.f, 0.f, 0.f, 0.f};
        size_t base = (size_t)blockIdx.x * 1440;
        for (int i = threadIdx.x; i < 1440; i += 256) {
            f4 v = w4[base + i];
            s.x += v.x; s.y += v.y; s.z += v.z; s.w += v.w;
        }
        asm volatile("" :: "v"(s.x), "v"(s.y), "v"(s.z), "v"(s.w));
    }
}

// ---------------- K2: per-graph pipeline: A^2 -> conv1..conv3 + pools [round-9, unchanged] ----------------
__global__ __launch_bounds__(256, 1) void k_graph(
    const float* __restrict__ A, const float* __restrict__ x,
    const float* __restrict__ W1, const float* __restrict__ b1,
    const float* __restrict__ Wc, const float* __restrict__ bc,
    float* __restrict__ Xp2, float* __restrict__ Xh2,
    float* __restrict__ Zp, float* __restrict__ Zp3, unsigned* __restrict__ cnt)
{
    const int b = blockIdx.x, g = b & 63, half = b >> 6;
    const int i0 = half * 64, i0p = 64 - i0;
    const int t = threadIdx.x;

    __shared__ float Bs[NPG * 132];
    __shared__ float A2s[64 * 132];
    __shared__ float Ps[64 * 132];
    __shared__ float xg[NPG * FIN];
    __shared__ float p2f[NPG * 8];
    __shared__ float W1s[FIN * WID];
    __shared__ float b1s[WID];

    {
        const float* Ag = A + (size_t)g * NPG * NPG;
        for (int e4 = t; e4 < 4096; e4 += 256) {
            int r = e4 >> 5, c4 = (e4 & 31) * 4;
            *(float4*)&Bs[r * 132 + c4] = *(const float4*)&Ag[r * NPG + c4];
        }
        const float* xp = x + g * NPG * FIN;
        for (int e = t; e < NPG * FIN; e += 256) xg[e] = xp[e];
        for (int e = t; e < FIN * WID; e += 256) W1s[e] = W1[e];
        if (t < WID) b1s[t] = b1[t];
    }
    __syncthreads();

    const int ty = t >> 4, tx = t & 15;
    const int r0 = ty * 4, cj = tx * 8;

    {
        float acc[4][8] = {};
        for (int k = 0; k < NPG; ++k) {
            float a[4];
            #pragma unroll
            for (int r = 0; r < 4; ++r) a[r] = Bs[(i0 + r0 + r) * 132 + k];
            float4 q0 = *(const float4*)&Bs[k * 132 + cj];
            float4 q1 = *(const float4*)&Bs[k * 132 + cj + 4];
            float bb[8] = {q0.x, q0.y, q0.z, q0.w, q1.x, q1.y, q1.z, q1.w};
            #pragma unroll
            for (int r = 0; r < 4; ++r)
                #pragma unroll
                for (int c = 0; c < 8; ++c)
                    acc[r][c] = fmaf(a[r], bb[c], acc[r][c]);
        }
        #pragma unroll
        for (int r = 0; r < 4; ++r) {
            *(float4*)&A2s[(r0 + r) * 132 + cj]     = make_float4(acc[r][0], acc[r][1], acc[r][2], acc[r][3]);
            *(float4*)&A2s[(r0 + r) * 132 + cj + 4] = make_float4(acc[r][4], acc[r][5], acc[r][6], acc[r][7]);
        }
    }
    __syncthreads();

    for (int e = t; e < 64 * FIN; e += 256) {
        int i = e / FIN, d = e - (e / FIN) * FIN;
        float s = 0.f;
        for (int k = 0; k < NPG; ++k) s = fmaf(A2s[i * 132 + k], xg[k * FIN + d], s);
        p2f[(i0 + i) * 8 + d] = s;
        __hip_atomic_store(&Xp2[g * 1024 + (i0 + i) * 8 + d], s, __ATOMIC_RELAXED, AGENT);
    }
    gbar(cnt + g * 2 + 0, 2u);
    for (int e = t; e < 64 * FIN; e += 256) {
        int i = e / FIN, d = e - (e / FIN) * FIN;
        p2f[(i0p + i) * 8 + d] =
            __hip_atomic_load(&Xp2[g * 1024 + (i0p + i) * 8 + d], __ATOMIC_RELAXED, AGENT);
    }
    __syncthreads();
    for (int e = t; e < NPG * WID; e += 256) {
        int i = e >> 7, o = e & 127;
        float s = b1s[o];
        #pragma unroll
        for (int d = 0; d < FIN; ++d) s = fmaf(p2f[i * 8 + d], W1s[d * WID + o], s);
        Bs[i * 132 + o] = leaky(s);
    }
    __syncthreads();
    if (half == 0 && t < WID) {
        float sm = 0.f, mx = -BIG;
        for (int i = 0; i < NPG; ++i) { float v = Bs[i * 132 + t]; sm += v; mx = fmaxf(mx, v); }
        Zp[g * D2 + t]       = sm * (1.f / NPG);
        Zp[g * D2 + WID + t] = mx;
    }

    {
        float acc[4][8] = {};
        for (int k = 0; k < NPG; ++k) {
            float a[4];
            #pragma unroll
            for (int r = 0; r < 4; ++r) a[r] = A2s[(r0 + r) * 132 + k];
            float4 q0 = *(const float4*)&Bs[k * 132 + cj];
            float4 q1 = *(const float4*)&Bs[k * 132 + cj + 4];
            float bb[8] = {q0.x, q0.y, q0.z, q0.w, q1.x, q1.y, q1.z, q1.w};
            #pragma unroll
            for (int r = 0; r < 4; ++r)
                #pragma unroll
                for (int c = 0; c < 8; ++c)
                    acc[r][c] = fmaf(a[r], bb[c], acc[r][c]);
        }
        #pragma unroll
        for (int r = 0; r < 4; ++r) {
            *(float4*)&Ps[(r0 + r) * 132 + cj]     = make_float4(acc[r][0], acc[r][1], acc[r][2], acc[r][3]);
            *(float4*)&Ps[(r0 + r) * 132 + cj + 4] = make_float4(acc[r][4], acc[r][5], acc[r][6], acc[r][7]);
        }
        __syncthreads();
        float o2[4][8] = {};
        const float* W2 = Wc;
        for (int d = 0; d < NPG; ++d) {
            float a[4];
            #pragma unroll
            for (int r = 0; r < 4; ++r) a[r] = Ps[(r0 + r) * 132 + d];
            float4 w0 = *(const float4*)&W2[d * WID + cj];
            float4 w1 = *(const float4*)&W2[d * WID + cj + 4];
            float bb[8] = {w0.x, w0.y, w0.z, w0.w, w1.x, w1.y, w1.z, w1.w};
            #pragma unroll
            for (int r = 0; r < 4; ++r)
                #pragma unroll
                for (int c = 0; c < 8; ++c)
                    o2[r][c] = fmaf(a[r], bb[c], o2[r][c]);
        }
        #pragma unroll
        for (int r = 0; r < 4; ++r)
            #pragma unroll
            for (int c = 0; c < 8; ++c)
                Bs[(i0 + r0 + r) * 132 + cj + c] = leaky(o2[r][c] + bc[cj + c]);
    }
    __syncthreads();
    for (int e = t; e < 64 * WID; e += 256) {
        int i = i0 + (e >> 7), o = e & 127;
        __hip_atomic_store(&Xh2[(size_t)g * 16384 + i * WID + o], Bs[i * 132 + o],
                           __ATOMIC_RELAXED, AGENT);
    }
    gbar(cnt + g * 2 + 1, 2u);
    for (int e = t; e < 64 * WID; e += 256) {
        int i = i0p + (e >> 7), o = e & 127;
        Bs[i * 132 + o] =
            __hip_atomic_load(&Xh2[(size_t)g * 16384 + i * WID + o], __ATOMIC_RELAXED, AGENT);
    }
    __syncthreads();
    if (half == 0 && t < WID) {
        float sm = 0.f, mx = -BIG;
        for (int i = 0; i < NPG; ++i) { float v = Bs[i * 132 + t]; sm += v; mx = fmaxf(mx, v); }
        Zp[g * D2 + 256 + t]       = sm * (1.f / NPG);
        Zp[g * D2 + 256 + WID + t] = mx;
    }

    {
        float acc[4][8] = {};
        for (int k = 0; k < NPG; ++k) {
            float a[4];
            #pragma unroll
            for (int r = 0; r < 4; ++r) a[r] = A2s[(r0 + r) * 132 + k];
            float4 q0 = *(const float4*)&Bs[k * 132 + cj];
            float4 q1 = *(const float4*)&Bs[k * 132 + cj + 4];
            float bb[8] = {q0.x, q0.y, q0.z, q0.w, q1.x, q1.y, q1.z, q1.w};
            #pragma unroll
            for (int r = 0; r < 4; ++r)
                #pragma unroll
                for (int c = 0; c < 8; ++c)
                    acc[r][c] = fmaf(a[r], bb[c], acc[r][c]);
        }
        __syncthreads();
        #pragma unroll
        for (int r = 0; r < 4; ++r) {
            *(float4*)&Ps[(r0 + r) * 132 + cj]     = make_float4(acc[r][0], acc[r][1], acc[r][2], acc[r][3]);
            *(float4*)&Ps[(r0 + r) * 132 + cj + 4] = make_float4(acc[r][4], acc[r][5], acc[r][6], acc[r][7]);
        }
        __syncthreads();
        float o3[4][8] = {};
        const float* W3 = Wc + WID * WID;
        const float* b3 = bc + WID;
        for (int d = 0; d < NPG; ++d) {
            float a[4];
            #pragma unroll
            for (int r = 0; r < 4; ++r) a[r] = Ps[(r0 + r) * 132 + d];
            float4 w0 = *(const float4*)&W3[d * WID + cj];
            float4 w1 = *(const float4*)&W3[d * WID + cj + 4];
            float bb[8] = {w0.x, w0.y, w0.z, w0.w, w1.x, w1.y, w1.z, w1.w};
            #pragma unroll
            for (int r = 0; r < 4; ++r)
                #pragma unroll
                for (int c = 0; c < 8; ++c)
                    o3[r][c] = fmaf(a[r], bb[c], o3[r][c]);
        }
        __syncthreads();
        #pragma unroll
        for (int r = 0; r < 4; ++r)
            #pragma unroll
            for (int c = 0; c < 8; ++c)
                Ps[(r0 + r) * 132 + cj + c] = leaky(o3[r][c] + b3[cj + c]);
    }
    __syncthreads();
    if (t < WID) {
        float sm = 0.f, mx = -BIG;
        for (int i = 0; i < 64; ++i) { float v = Ps[i * 132 + t]; sm += v; mx = fmaxf(mx, v); }
        Zp3[(size_t)(g * 2 + half) * 256 + t]       = sm;
        Zp3[(size_t)(g * 2 + half) * 256 + 128 + t] = mx;
    }
}

// ---------------- K3: tail: BN + 5 MLP layers + head. grid 48, block 256 ----------------
__device__ __forceinline__ float bn_val(const float* Zp, const float* Zp3, int c, int r)
{
    if (c < 512) return Zp[r * D2 + c];
    int o = c - 512;
    if (o < 128)
        return (Zp3[(size_t)(r * 2) * 256 + o] + Zp3[(size_t)(r * 2 + 1) * 256 + o]) * (1.f / NPG);
    o -= 128;
    return fmaxf(Zp3[(size_t)(r * 2) * 256 + 128 + o], Zp3[(size_t)(r * 2 + 1) * 256 + 128 + o]);
}

// z-chunk prefetch (8 f4/thread) and swizzled LDS store
#define PFZ(c) { \
    _Pragma("unroll") \
    for (int i = 0; i < 8; ++i) { \
        int idx = t + i * 256, kk = idx >> 4, r4 = (idx & 15) * 4; \
        pf[i] = *(const f4*)&zin[((c) * 128 + kk) * NG + r4]; \
    } }
#define STZ(buf) { \
    _Pragma("unroll") \
    for (int i = 0; i < 8; ++i) { \
        int idx = t + i * 256, kk = idx >> 4, r4 = (idx & 15) * 4; \
        _Pragma("unroll") \
        for (int j = 0; j < 4; ++j) { \
            int rr = r4 + j; \
            zc[buf][rr * 128 + (((kk >> 2) ^ (rr & 7)) << 2) + (kk & 3)] = pf[i][j]; \
        } } }

__global__ __launch_bounds__(256, 1) void k_tail(
    const float* __restrict__ Zp, const float* __restrict__ Zp3,
    const float* __restrict__ bng, const float* __restrict__ bnb,
    const float* __restrict__ linW, const float* __restrict__ linb,
    const float* __restrict__ outW, const float* __restrict__ outb,
    float* __restrict__ ZT0, float* __restrict__ ZT1,
    float* __restrict__ out, unsigned* __restrict__ cnt)
{
    const int b = blockIdx.x;        // 48 blocks x 16 cols
    const int t = threadIdx.x;
    const int c0 = b * 16;
    __shared__ float Wp[D2 * 16];    // 49 KB: W panel (also BN scratch)
    __shared__ float zc[2][64 * 128];// 65.5 KB: z chunks, XOR-swizzled, double-buffered
    __shared__ float red[4 * 64];

    const int w = t >> 6, r = t & 63;   // wave -> 4 cols, lane -> row

    // ---- BN + transpose -> ZT0 (plain stores; gbar release makes them visible) ----
    {
        int sub = t >> 4, rq = t & 15;
        int c = c0 + sub;
        float s = 0.f, s2 = 0.f;
        #pragma unroll
        for (int rr = 0; rr < 4; ++rr) {
            float v = bn_val(Zp, Zp3, c, rq * 4 + rr);
            s += v; s2 = fmaf(v, v, s2);
        }
        Wp[sub * 16 + rq] = s;
        Wp[256 + sub * 16 + rq] = s2;
        __syncthreads();
        if (t < 16) {
            float ss = 0.f, qq = 0.f;
            #pragma unroll
            for (int q = 0; q < 16; ++q) { ss += Wp[t * 16 + q]; qq += Wp[256 + t * 16 + q]; }
            float m   = ss * (1.f / NG);
            float var = qq * (1.f / NG) - m * m;
            Wp[512 + t] = m;
            Wp[528 + t] = rsqrtf(var + BNEPS) * bng[c0 + t];
            Wp[544 + t] = bnb[c0 + t];
        }
        __syncthreads();
        float m = Wp[512 + sub], sc = Wp[528 + sub], bt = Wp[544 + sub];
        #pragma unroll
        for (int rr = 0; rr < 4; ++rr) {
            int rx = rq * 4 + rr;
            float v = bn_val(Zp, Zp3, c, rx);
            ZT0[c * NG + rx] = (v - m) * sc + bt;
        }
    }

    // ---- prefetch layer-0 W panel into registers BEFORE the BN barrier ----
    f4 wpf[12];
    {
        const float* Wl = linW;
        #pragma unroll
        for (int i = 0; i < 12; ++i) {
            int e4 = t + i * 256, k = e4 >> 2, cp = e4 & 3;
            wpf[i] = *(const f4*)&Wl[(size_t)k * D2 + c0 + cp * 4];
        }
    }
    gbar(cnt + 128, 48u);

    // ---- 5 MLP layers ----
    f4 pf[8];
    for (int l = 0; l < 5; ++l) {
        const float* zin  = (l & 1) ? ZT1 : ZT0;
        float*       zout = (l & 1) ? ZT0 : ZT1;
        __syncthreads();                  // Wp scratch free (BN / prev layer done at gbar)
        #pragma unroll
        for (int i = 0; i < 12; ++i) {    // panel regs -> LDS
            int e4 = t + i * 256, k = e4 >> 2, cp = e4 & 3;
            *(f4*)&Wp[k * 16 + cp * 4] = wpf[i];
        }
        PFZ(0)
        __syncthreads();                  // Wp ready
        STZ(0)
        PFZ(1)
        __syncthreads();                  // zc[0] ready
        float acc[4] = {0.f, 0.f, 0.f, 0.f};
        for (int kb = 0; kb < 6; ++kb) {
            const float* zcur = zc[kb & 1];
            #pragma unroll 8
            for (int k4 = 0; k4 < 32; ++k4) {
                f4 z4 = *(const f4*)&zcur[r * 128 + ((k4 ^ (r & 7)) << 2)];
                int kg = kb * 128 + k4 * 4;
                f4 w0 = *(const f4*)&Wp[(kg + 0) * 16 + w * 4];
                f4 w1 = *(const f4*)&Wp[(kg + 1) * 16 + w * 4];
                f4 w2 = *(const f4*)&Wp[(kg + 2) * 16 + w * 4];
                f4 w3 = *(const f4*)&Wp[(kg + 3) * 16 + w * 4];
                acc[0] = fmaf(z4.x, w0.x, acc[0]); acc[1] = fmaf(z4.x, w0.y, acc[1]);
                acc[2] = fmaf(z4.x, w0.z, acc[2]); acc[3] = fmaf(z4.x, w0.w, acc[3]);
                acc[0] = fmaf(z4.y, w1.x, acc[0]); acc[1] = fmaf(z4.y, w1.y, acc[1]);
                acc[2] = fmaf(z4.y, w1.z, acc[2]); acc[3] = fmaf(z4.y, w1.w, acc[3]);
                acc[0] = fmaf(z4.z, w2.x, acc[0]); acc[1] = fmaf(z4.z, w2.y, acc[1]);
                acc[2] = fmaf(z4.z, w2.z, acc[2]); acc[3] = fmaf(z4.z, w2.w, acc[3]);
                acc[0] = fmaf(z4.w, w3.x, acc[0]); acc[1] = fmaf(z4.w, w3.y, acc[1]);
                acc[2] = fmaf(z4.w, w3.z, acc[2]); acc[3] = fmaf(z4.w, w3.w, acc[3]);
            }
            if (kb < 5) {
                STZ((kb + 1) & 1)         // pf holds chunk kb+1
                if (kb < 4) PFZ(kb + 2)
                __syncthreads();
            }
        }
        #pragma unroll
        for (int cc = 0; cc < 4; ++cc) {  // plain coalesced stores
            int c = c0 + w * 4 + cc;
            zout[c * NG + r] = leaky(acc[cc] + linb[l * D2 + c]);
        }
        if (l < 4) {                      // prefetch next panel BEFORE the gbar
            const float* Wl = linW + (size_t)(l + 1) * D2 * D2;
            #pragma unroll
            for (int i = 0; i < 12; ++i) {
                int e4 = t + i * 256, k = e4 >> 2, cp = e4 & 3;
                wpf[i] = *(const f4*)&Wl[(size_t)k * D2 + c0 + cp * 4];
            }
        }
        gbar(cnt + 129 + l, 48u);
    }

    // ---- head (block 0) ----
    if (b == 0) {
        for (int e = t; e < D2; e += 256) Wp[e] = outW[e];
        __syncthreads();
        int kq = t >> 6, rr = t & 63;
        const float* zf = ZT1;            // after 5 layers
        float s = 0.f;
        #pragma unroll 16
        for (int k = kq * 192; k < kq * 192 + 192; ++k)
            s = fmaf(zf[k * NG + rr], Wp[k], s);
        red[kq * 64 + rr] = s;
        __syncthreads();
        if (t < 64)
            out[t] = red[t] + red[64 + t] + red[128 + t] + red[192 + t] + outb[0];
    }
}

extern "C" void kernel_launch(void* const* d_in, const int* in_sizes, int n_in,
                              void* d_out, int out_size, void* d_ws, size_t ws_size,
                              hipStream_t stream)
{
    (void)in_sizes; (void)n_in; (void)out_size; (void)ws_size;
    const float* x       = (const float*)d_in[0];
    // d_in[1] = batch: fixed structure (i/128), unused
    const float* conv1_W = (const float*)d_in[2];
    const float* conv1_b = (const float*)d_in[3];
    const float* convs_W = (const float*)d_in[4];
    const float* convs_b = (const float*)d_in[5];
    const float* bn_g    = (const float*)d_in[6];
    const float* bn_b    = (const float*)d_in[7];
    const float* lin_W   = (const float*)d_in[8];
    const float* lin_b   = (const float*)d_in[9];
    const float* out_W   = (const float*)d_in[10];
    const float* out_b   = (const float*)d_in[11];

    float* f = (float*)d_ws;
    float* A   = f;                      // 1M floats
    float* Xh2 = f + (1 << 20);          // 1M
    float* Xp2 = f + (2 << 20);          // 65536
    float* Zp  = Xp2 + 65536;            // 49152
    float* Zp3 = Zp + NG * D2;           // 32768
    float* ZT0 = Zp3 + 32768;            // 49152
    float* ZT1 = ZT0 + NG * D2;          // 49152
    unsigned* cnt = (unsigned*)(f + (4 << 20));   // 16 MB offset; counters
    float* outp = (float*)d_out;

    hipMemsetAsync(cnt, 0, 1024, stream);
    k_knn  <<<dim3(512), dim3(256), 0, stream>>>(x, A, lin_W);
    k_graph<<<dim3(128), dim3(256), 0, stream>>>(A, x, conv1_W, conv1_b, convs_W, convs_b,
                                                 Xp2, Xh2, Zp, Zp3, cnt);
    k_tail <<<dim3(48),  dim3(256), 0, stream>>>(Zp, Zp3, bn_g, bn_b, lin_W, lin_b,
                                                 out_W, out_b, ZT0, ZT1, outp, cnt);
}

// Round 11
// 246.645 us; speedup vs baseline: 1.0516x; 1.0516x over previous
//
#include <hip/hip_runtime.h>

#define NG    64
#define NPG   128
#define KNN   100
#define FIN   6
#define WID   128
#define D2    768
#define NEG   0.01f
#define INV101 (1.0f/101.0f)
#define BNEPS 1e-5f
#define BIG   1e30f

#define AGENT __HIP_MEMORY_SCOPE_AGENT

typedef float f4 __attribute__((ext_vector_type(4)));

__device__ __forceinline__ float leaky(float v) { return v > 0.f ? v : NEG * v; }

// barrier among `target` blocks on counter c (counter must be 0 before first use).
// agent-scope acq_rel/acquire => L2 writeback on release, L2 inv on acquire.
__device__ __forceinline__ void gbar(unsigned* c, unsigned target) {
    __syncthreads();
    if (threadIdx.x == 0) {
        __hip_atomic_fetch_add(c, 1u, __ATOMIC_ACQ_REL, AGENT);
        while (__hip_atomic_load(c, __ATOMIC_ACQUIRE, AGENT) < target)
            __builtin_amdgcn_s_sleep(2);
    }
    __syncthreads();
}

// ---------------- K1: kNN (rank-select) + A = (I+M)/101 [round-9 passing code] ----------------
__global__ __launch_bounds__(256) void k_knn(const float* __restrict__ x, float* __restrict__ A)
{
    int g  = blockIdx.x >> 3;
    int i0 = (blockIdx.x & 7) * 16;
    __shared__ float xg[NPG * FIN];
    __shared__ float sq[NPG];
    __shared__ float D[16][NPG];
    const float* xp = x + g * NPG * FIN;
    for (int t = threadIdx.x; t < NPG * FIN; t += 256) xg[t] = xp[t];
    __syncthreads();
    if (threadIdx.x < NPG) {
        float s = 0.f;
        #pragma unroll
        for (int c = 0; c < FIN; ++c) { float v = xg[threadIdx.x * FIN + c]; s = fmaf(v, v, s); }
        sq[threadIdx.x] = s;
    }
    __syncthreads();
    for (int e = threadIdx.x; e < 16 * NPG; e += 256) {
        int il = e >> 7, j = e & 127;
        int i = i0 + il;
        float d;
        if (j == i) d = BIG;
        else {
            float dot = 0.f;
            #pragma unroll
            for (int c = 0; c < FIN; ++c) dot = fmaf(xg[i * FIN + c], xg[j * FIN + c], dot);
            d = sq[i] + sq[j] - 2.f * dot;
        }
        D[il][j] = d;
    }
    __syncthreads();
    float* Ag = A + (size_t)g * NPG * NPG;
    for (int e = threadIdx.x; e < 16 * NPG; e += 256) {
        int il = e >> 7, j = e & 127;
        int i = i0 + il;
        float aval;
        if (i == j) aval = INV101;
        else {
            float dj = D[il][j];
            int cnt = 0;
            #pragma unroll 8
            for (int k = 0; k < NPG; ++k) {
                float dk = D[il][k];
                cnt += (dk < dj || (dk == dj && k < j)) ? 1 : 0;
            }
            aval = (cnt < KNN) ? INV101 : 0.f;
        }
        Ag[i * NPG + j] = aval;
    }
}

// ---------------- K2: per-graph pipeline: A^2 -> conv1..conv3 + pools [round-9, unchanged] ----------------
__global__ __launch_bounds__(256, 1) void k_graph(
    const float* __restrict__ A, const float* __restrict__ x,
    const float* __restrict__ W1, const float* __restrict__ b1,
    const float* __restrict__ Wc, const float* __restrict__ bc,
    float* __restrict__ Xp2, float* __restrict__ Xh2,
    float* __restrict__ Zp, float* __restrict__ Zp3, unsigned* __restrict__ cnt)
{
    const int b = blockIdx.x, g = b & 63, half = b >> 6;
    const int i0 = half * 64, i0p = 64 - i0;
    const int t = threadIdx.x;

    __shared__ float Bs[NPG * 132];
    __shared__ float A2s[64 * 132];
    __shared__ float Ps[64 * 132];
    __shared__ float xg[NPG * FIN];
    __shared__ float p2f[NPG * 8];
    __shared__ float W1s[FIN * WID];
    __shared__ float b1s[WID];

    {
        const float* Ag = A + (size_t)g * NPG * NPG;
        for (int e4 = t; e4 < 4096; e4 += 256) {
            int r = e4 >> 5, c4 = (e4 & 31) * 4;
            *(float4*)&Bs[r * 132 + c4] = *(const float4*)&Ag[r * NPG + c4];
        }
        const float* xp = x + g * NPG * FIN;
        for (int e = t; e < NPG * FIN; e += 256) xg[e] = xp[e];
        for (int e = t; e < FIN * WID; e += 256) W1s[e] = W1[e];
        if (t < WID) b1s[t] = b1[t];
    }
    __syncthreads();

    const int ty = t >> 4, tx = t & 15;
    const int r0 = ty * 4, cj = tx * 8;

    {
        float acc[4][8] = {};
        for (int k = 0; k < NPG; ++k) {
            float a[4];
            #pragma unroll
            for (int r = 0; r < 4; ++r) a[r] = Bs[(i0 + r0 + r) * 132 + k];
            float4 q0 = *(const float4*)&Bs[k * 132 + cj];
            float4 q1 = *(const float4*)&Bs[k * 132 + cj + 4];
            float bb[8] = {q0.x, q0.y, q0.z, q0.w, q1.x, q1.y, q1.z, q1.w};
            #pragma unroll
            for (int r = 0; r < 4; ++r)
                #pragma unroll
                for (int c = 0; c < 8; ++c)
                    acc[r][c] = fmaf(a[r], bb[c], acc[r][c]);
        }
        #pragma unroll
        for (int r = 0; r < 4; ++r) {
            *(float4*)&A2s[(r0 + r) * 132 + cj]     = make_float4(acc[r][0], acc[r][1], acc[r][2], acc[r][3]);
            *(float4*)&A2s[(r0 + r) * 132 + cj + 4] = make_float4(acc[r][4], acc[r][5], acc[r][6], acc[r][7]);
        }
    }
    __syncthreads();

    for (int e = t; e < 64 * FIN; e += 256) {
        int i = e / FIN, d = e - (e / FIN) * FIN;
        float s = 0.f;
        for (int k = 0; k < NPG; ++k) s = fmaf(A2s[i * 132 + k], xg[k * FIN + d], s);
        p2f[(i0 + i) * 8 + d] = s;
        __hip_atomic_store(&Xp2[g * 1024 + (i0 + i) * 8 + d], s, __ATOMIC_RELAXED, AGENT);
    }
    gbar(cnt + g * 2 + 0, 2u);
    for (int e = t; e < 64 * FIN; e += 256) {
        int i = e / FIN, d = e - (e / FIN) * FIN;
        p2f[(i0p + i) * 8 + d] =
            __hip_atomic_load(&Xp2[g * 1024 + (i0p + i) * 8 + d], __ATOMIC_RELAXED, AGENT);
    }
    __syncthreads();
    for (int e = t; e < NPG * WID; e += 256) {
        int i = e >> 7, o = e & 127;
        float s = b1s[o];
        #pragma unroll
        for (int d = 0; d < FIN; ++d) s = fmaf(p2f[i * 8 + d], W1s[d * WID + o], s);
        Bs[i * 132 + o] = leaky(s);
    }
    __syncthreads();
    if (half == 0 && t < WID) {
        float sm = 0.f, mx = -BIG;
        for (int i = 0; i < NPG; ++i) { float v = Bs[i * 132 + t]; sm += v; mx = fmaxf(mx, v); }
        Zp[g * D2 + t]       = sm * (1.f / NPG);
        Zp[g * D2 + WID + t] = mx;
    }

    {
        float acc[4][8] = {};
        for (int k = 0; k < NPG; ++k) {
            float a[4];
            #pragma unroll
            for (int r = 0; r < 4; ++r) a[r] = A2s[(r0 + r) * 132 + k];
            float4 q0 = *(const float4*)&Bs[k * 132 + cj];
            float4 q1 = *(const float4*)&Bs[k * 132 + cj + 4];
            float bb[8] = {q0.x, q0.y, q0.z, q0.w, q1.x, q1.y, q1.z, q1.w};
            #pragma unroll
            for (int r = 0; r < 4; ++r)
                #pragma unroll
                for (int c = 0; c < 8; ++c)
                    acc[r][c] = fmaf(a[r], bb[c], acc[r][c]);
        }
        #pragma unroll
        for (int r = 0; r < 4; ++r) {
            *(float4*)&Ps[(r0 + r) * 132 + cj]     = make_float4(acc[r][0], acc[r][1], acc[r][2], acc[r][3]);
            *(float4*)&Ps[(r0 + r) * 132 + cj + 4] = make_float4(acc[r][4], acc[r][5], acc[r][6], acc[r][7]);
        }
        __syncthreads();
        float o2[4][8] = {};
        const float* W2 = Wc;
        for (int d = 0; d < NPG; ++d) {
            float a[4];
            #pragma unroll
            for (int r = 0; r < 4; ++r) a[r] = Ps[(r0 + r) * 132 + d];
            float4 w0 = *(const float4*)&W2[d * WID + cj];
            float4 w1 = *(const float4*)&W2[d * WID + cj + 4];
            float bb[8] = {w0.x, w0.y, w0.z, w0.w, w1.x, w1.y, w1.z, w1.w};
            #pragma unroll
            for (int r = 0; r < 4; ++r)
                #pragma unroll
                for (int c = 0; c < 8; ++c)
                    o2[r][c] = fmaf(a[r], bb[c], o2[r][c]);
        }
        #pragma unroll
        for (int r = 0; r < 4; ++r)
            #pragma unroll
            for (int c = 0; c < 8; ++c)
                Bs[(i0 + r0 + r) * 132 + cj + c] = leaky(o2[r][c] + bc[cj + c]);
    }
    __syncthreads();
    for (int e = t; e < 64 * WID; e += 256) {
        int i = i0 + (e >> 7), o = e & 127;
        __hip_atomic_store(&Xh2[(size_t)g * 16384 + i * WID + o], Bs[i * 132 + o],
                           __ATOMIC_RELAXED, AGENT);
    }
    gbar(cnt + g * 2 + 1, 2u);
    for (int e = t; e < 64 * WID; e += 256) {
        int i = i0p + (e >> 7), o = e & 127;
        Bs[i * 132 + o] =
            __hip_atomic_load(&Xh2[(size_t)g * 16384 + i * WID + o], __ATOMIC_RELAXED, AGENT);
    }
    __syncthreads();
    if (half == 0 && t < WID) {
        float sm = 0.f, mx = -BIG;
        for (int i = 0; i < NPG; ++i) { float v = Bs[i * 132 + t]; sm += v; mx = fmaxf(mx, v); }
        Zp[g * D2 + 256 + t]       = sm * (1.f / NPG);
        Zp[g * D2 + 256 + WID + t] = mx;
    }

    {
        float acc[4][8] = {};
        for (int k = 0; k < NPG; ++k) {
            float a[4];
            #pragma unroll
            for (int r = 0; r < 4; ++r) a[r] = A2s[(r0 + r) * 132 + k];
            float4 q0 = *(const float4*)&Bs[k * 132 + cj];
            float4 q1 = *(const float4*)&Bs[k * 132 + cj + 4];
            float bb[8] = {q0.x, q0.y, q0.z, q0.w, q1.x, q1.y, q1.z, q1.w};
            #pragma unroll
            for (int r = 0; r < 4; ++r)
                #pragma unroll
                for (int c = 0; c < 8; ++c)
                    acc[r][c] = fmaf(a[r], bb[c], acc[r][c]);
        }
        __syncthreads();
        #pragma unroll
        for (int r = 0; r < 4; ++r) {
            *(float4*)&Ps[(r0 + r) * 132 + cj]     = make_float4(acc[r][0], acc[r][1], acc[r][2], acc[r][3]);
            *(float4*)&Ps[(r0 + r) * 132 + cj + 4] = make_float4(acc[r][4], acc[r][5], acc[r][6], acc[r][7]);
        }
        __syncthreads();
        float o3[4][8] = {};
        const float* W3 = Wc + WID * WID;
        const float* b3 = bc + WID;
        for (int d = 0; d < NPG; ++d) {
            float a[4];
            #pragma unroll
            for (int r = 0; r < 4; ++r) a[r] = Ps[(r0 + r) * 132 + d];
            float4 w0 = *(const float4*)&W3[d * WID + cj];
            float4 w1 = *(const float4*)&W3[d * WID + cj + 4];
            float bb[8] = {w0.x, w0.y, w0.z, w0.w, w1.x, w1.y, w1.z, w1.w};
            #pragma unroll
            for (int r = 0; r < 4; ++r)
                #pragma unroll
                for (int c = 0; c < 8; ++c)
                    o3[r][c] = fmaf(a[r], bb[c], o3[r][c]);
        }
        __syncthreads();
        #pragma unroll
        for (int r = 0; r < 4; ++r)
            #pragma unroll
            for (int c = 0; c < 8; ++c)
                Ps[(r0 + r) * 132 + cj + c] = leaky(o3[r][c] + b3[cj + c]);
    }
    __syncthreads();
    if (t < WID) {
        float sm = 0.f, mx = -BIG;
        for (int i = 0; i < 64; ++i) { float v = Ps[i * 132 + t]; sm += v; mx = fmaxf(mx, v); }
        Zp3[(size_t)(g * 2 + half) * 256 + t]       = sm;
        Zp3[(size_t)(g * 2 + half) * 256 + 128 + t] = mx;
    }
}

// ---------------- K3: tail: BN + 5 MLP layers + head. grid 48, block 256 ----------------
// MLP layer: wave w = k-slice [w*192, w*192+192), 16 cols/block, lane = row.
// W is wave-uniform -> s_load_dwordx16 per k; z is one coalesced dword load per k.
// LDS only for the 4-way split-K reduce (16 KB).
__device__ __forceinline__ float bn_val(const float* Zp, const float* Zp3, int c, int r)
{
    if (c < 512) return Zp[r * D2 + c];
    int o = c - 512;
    if (o < 128)
        return (Zp3[(size_t)(r * 2) * 256 + o] + Zp3[(size_t)(r * 2 + 1) * 256 + o]) * (1.f / NPG);
    o -= 128;
    return fmaxf(Zp3[(size_t)(r * 2) * 256 + 128 + o], Zp3[(size_t)(r * 2 + 1) * 256 + 128 + o]);
}

__global__ __launch_bounds__(256, 1) void k_tail(
    const float* __restrict__ Zp, const float* __restrict__ Zp3,
    const float* __restrict__ bng, const float* __restrict__ bnb,
    const float* __restrict__ linW, const float* __restrict__ linb,
    const float* __restrict__ outW, const float* __restrict__ outb,
    float* __restrict__ ZT0, float* __restrict__ ZT1,
    float* __restrict__ out, unsigned* __restrict__ cnt)
{
    const int b = blockIdx.x;        // 48 blocks x 16 cols
    const int t = threadIdx.x;
    const int c0 = b * 16;
    __shared__ float sc1[D2];        // BN scratch / head outW (3 KB)
    __shared__ float red[4 * 16 * 64]; // split-K partials (16 KB)

    // ---- BN + transpose -> ZT0 (plain stores; gbar release publishes) ----
    {
        int sub = t >> 4, rq = t & 15;
        int c = c0 + sub;
        float s = 0.f, s2 = 0.f;
        #pragma unroll
        for (int rr = 0; rr < 4; ++rr) {
            float v = bn_val(Zp, Zp3, c, rq * 4 + rr);
            s += v; s2 = fmaf(v, v, s2);
        }
        sc1[sub * 16 + rq] = s;
        sc1[256 + sub * 16 + rq] = s2;
        __syncthreads();
        if (t < 16) {
            float ss = 0.f, qq = 0.f;
            #pragma unroll
            for (int q = 0; q < 16; ++q) { ss += sc1[t * 16 + q]; qq += sc1[256 + t * 16 + q]; }
            float m   = ss * (1.f / NG);
            float var = qq * (1.f / NG) - m * m;
            sc1[512 + t] = m;
            sc1[528 + t] = rsqrtf(var + BNEPS) * bng[c0 + t];
            sc1[544 + t] = bnb[c0 + t];
        }
        __syncthreads();
        float m = sc1[512 + sub], sc = sc1[528 + sub], bt = sc1[544 + sub];
        #pragma unroll
        for (int rr = 0; rr < 4; ++rr) {
            int rx = rq * 4 + rr;
            float v = bn_val(Zp, Zp3, c, rx);
            ZT0[c * NG + rx] = (v - m) * sc + bt;
        }
    }
    gbar(cnt + 128, 48u);

    // ---- 5 MLP layers: split-K over waves, SGPR-broadcast W ----
    const int w = __builtin_amdgcn_readfirstlane(t >> 6);  // wave id (k-slice)
    const int r = t & 63;                                  // lane = row
    for (int l = 0; l < 5; ++l) {
        const float* zin  = (l & 1) ? ZT1 : ZT0;
        float*       zout = (l & 1) ? ZT0 : ZT1;
        const float* Wl = linW + (size_t)l * D2 * D2;
        const int k0 = w * 192;
        float acc[16];
        #pragma unroll
        for (int c = 0; c < 16; ++c) acc[c] = 0.f;
        for (int kk = 0; kk < 192; kk += 8) {
            float zv[8];
            #pragma unroll
            for (int u = 0; u < 8; ++u)
                zv[u] = zin[(k0 + kk + u) * NG + r];
            #pragma unroll
            for (int u = 0; u < 8; ++u) {
                const float* wk = Wl + (size_t)(k0 + kk + u) * D2 + c0;  // wave-uniform 64B line
                #pragma unroll
                for (int c = 0; c < 16; ++c)
                    acc[c] = fmaf(zv[u], wk[c], acc[c]);
            }
        }
        __syncthreads();                  // red free (prev layer reduce done)
        #pragma unroll
        for (int c = 0; c < 16; ++c)
            red[(w * 16 + c) * 64 + r] = acc[c];
        __syncthreads();
        {                                  // reduce 4 partials; thread -> (col, 4 rows)
            int c = t >> 4, rb = (t & 15) * 4;
            float bv = linb[l * D2 + c0 + c];
            f4 v;
            #pragma unroll
            for (int j = 0; j < 4; ++j) {
                int rr = rb + j;
                float s = red[(0 * 16 + c) * 64 + rr] + red[(1 * 16 + c) * 64 + rr]
                        + red[(2 * 16 + c) * 64 + rr] + red[(3 * 16 + c) * 64 + rr];
                v[j] = leaky(s + bv);
            }
            *(f4*)&zout[(c0 + c) * NG + rb] = v;
        }
        gbar(cnt + 129 + l, 48u);
    }

    // ---- head (block 0) ----
    if (b == 0) {
        for (int e = t; e < D2; e += 256) sc1[e] = outW[e];
        __syncthreads();
        int kq = t >> 6, rr = t & 63;
        const float* zf = ZT1;            // after 5 layers
        float s = 0.f;
        #pragma unroll 16
        for (int k = kq * 192; k < kq * 192 + 192; ++k)
            s = fmaf(zf[k * NG + rr], sc1[k], s);
        red[kq * 64 + rr] = s;
        __syncthreads();
        if (t < 64)
            out[t] = red[t] + red[64 + t] + red[128 + t] + red[192 + t] + outb[0];
    }
}

extern "C" void kernel_launch(void* const* d_in, const int* in_sizes, int n_in,
                              void* d_out, int out_size, void* d_ws, size_t ws_size,
                              hipStream_t stream)
{
    (void)in_sizes; (void)n_in; (void)out_size; (void)ws_size;
    const float* x       = (const float*)d_in[0];
    // d_in[1] = batch: fixed structure (i/128), unused
    const float* conv1_W = (const float*)d_in[2];
    const float* conv1_b = (const float*)d_in[3];
    const float* convs_W = (const float*)d_in[4];
    const float* convs_b = (const float*)d_in[5];
    const float* bn_g    = (const float*)d_in[6];
    const float* bn_b    = (const float*)d_in[7];
    const float* lin_W   = (const float*)d_in[8];
    const float* lin_b   = (const float*)d_in[9];
    const float* out_W   = (const float*)d_in[10];
    const float* out_b   = (const float*)d_in[11];

    float* f = (float*)d_ws;
    float* A   = f;                      // 1M floats
    float* Xh2 = f + (1 << 20);          // 1M
    float* Xp2 = f + (2 << 20);          // 65536
    float* Zp  = Xp2 + 65536;            // 49152
    float* Zp3 = Zp + NG * D2;           // 32768
    float* ZT0 = Zp3 + 32768;            // 49152
    float* ZT1 = ZT0 + NG * D2;          // 49152
    unsigned* cnt = (unsigned*)(f + (4 << 20));   // 16 MB offset; counters
    float* outp = (float*)d_out;

    hipMemsetAsync(cnt, 0, 1024, stream);
    k_knn  <<<dim3(512), dim3(256), 0, stream>>>(x, A);
    k_graph<<<dim3(128), dim3(256), 0, stream>>>(A, x, conv1_W, conv1_b, convs_W, convs_b,
                                                 Xp2, Xh2, Zp, Zp3, cnt);
    k_tail <<<dim3(48),  dim3(256), 0, stream>>>(Zp, Zp3, bn_g, bn_b, lin_W, lin_b,
                                                 out_W, out_b, ZT0, ZT1, outp, cnt);
}

// Round 12
// 218.094 us; speedup vs baseline: 1.1892x; 1.1309x over previous
//
#include <hip/hip_runtime.h>

#define NG    64
#define NPG   128
#define KNN   100
#define FIN   6
#define WID   128
#define D2    768
#define NEG   0.01f
#define INV101 (1.0f/101.0f)
#define BNEPS 1e-5f
#define BIG   1e30f

#define AGENT __HIP_MEMORY_SCOPE_AGENT

typedef float f4 __attribute__((ext_vector_type(4)));
typedef float f2 __attribute__((ext_vector_type(2)));

__device__ __forceinline__ float leaky(float v) { return v > 0.f ? v : NEG * v; }

// barrier among `target` blocks on counter c (counter must be 0 before first use).
// agent-scope acq_rel/acquire => L2 writeback on release, L2 inv on acquire.
__device__ __forceinline__ void gbar(unsigned* c, unsigned target) {
    __syncthreads();
    if (threadIdx.x == 0) {
        __hip_atomic_fetch_add(c, 1u, __ATOMIC_ACQ_REL, AGENT);
        while (__hip_atomic_load(c, __ATOMIC_ACQUIRE, AGENT) < target)
            __builtin_amdgcn_s_sleep(2);
    }
    __syncthreads();
}

// ---------------- K1: kNN (rank-select) + A = (I+M)/101 [round-9 passing code] ----------------
__global__ __launch_bounds__(256) void k_knn(const float* __restrict__ x, float* __restrict__ A)
{
    int g  = blockIdx.x >> 3;
    int i0 = (blockIdx.x & 7) * 16;
    __shared__ float xg[NPG * FIN];
    __shared__ float sq[NPG];
    __shared__ float D[16][NPG];
    const float* xp = x + g * NPG * FIN;
    for (int t = threadIdx.x; t < NPG * FIN; t += 256) xg[t] = xp[t];
    __syncthreads();
    if (threadIdx.x < NPG) {
        float s = 0.f;
        #pragma unroll
        for (int c = 0; c < FIN; ++c) { float v = xg[threadIdx.x * FIN + c]; s = fmaf(v, v, s); }
        sq[threadIdx.x] = s;
    }
    __syncthreads();
    for (int e = threadIdx.x; e < 16 * NPG; e += 256) {
        int il = e >> 7, j = e & 127;
        int i = i0 + il;
        float d;
        if (j == i) d = BIG;
        else {
            float dot = 0.f;
            #pragma unroll
            for (int c = 0; c < FIN; ++c) dot = fmaf(xg[i * FIN + c], xg[j * FIN + c], dot);
            d = sq[i] + sq[j] - 2.f * dot;
        }
        D[il][j] = d;
    }
    __syncthreads();
    float* Ag = A + (size_t)g * NPG * NPG;
    for (int e = threadIdx.x; e < 16 * NPG; e += 256) {
        int il = e >> 7, j = e & 127;
        int i = i0 + il;
        float aval;
        if (i == j) aval = INV101;
        else {
            float dj = D[il][j];
            int cnt = 0;
            #pragma unroll 8
            for (int k = 0; k < NPG; ++k) {
                float dk = D[il][k];
                cnt += (dk < dj || (dk == dj && k < j)) ? 1 : 0;
            }
            aval = (cnt < KNN) ? INV101 : 0.f;
        }
        Ag[i * NPG + j] = aval;
    }
}

// ---------------- K2: per-graph pipeline: A^2 -> conv1..conv3 + pools [round-11, unchanged] ----------------
__global__ __launch_bounds__(256, 1) void k_graph(
    const float* __restrict__ A, const float* __restrict__ x,
    const float* __restrict__ W1, const float* __restrict__ b1,
    const float* __restrict__ Wc, const float* __restrict__ bc,
    float* __restrict__ Xp2, float* __restrict__ Xh2,
    float* __restrict__ Zp, float* __restrict__ Zp3, unsigned* __restrict__ cnt)
{
    const int b = blockIdx.x, g = b & 63, half = b >> 6;
    const int i0 = half * 64, i0p = 64 - i0;
    const int t = threadIdx.x;

    __shared__ float Bs[NPG * 132];
    __shared__ float A2s[64 * 132];
    __shared__ float Ps[64 * 132];
    __shared__ float xg[NPG * FIN];
    __shared__ float p2f[NPG * 8];
    __shared__ float W1s[FIN * WID];
    __shared__ float b1s[WID];

    {
        const float* Ag = A + (size_t)g * NPG * NPG;
        for (int e4 = t; e4 < 4096; e4 += 256) {
            int r = e4 >> 5, c4 = (e4 & 31) * 4;
            *(float4*)&Bs[r * 132 + c4] = *(const float4*)&Ag[r * NPG + c4];
        }
        const float* xp = x + g * NPG * FIN;
        for (int e = t; e < NPG * FIN; e += 256) xg[e] = xp[e];
        for (int e = t; e < FIN * WID; e += 256) W1s[e] = W1[e];
        if (t < WID) b1s[t] = b1[t];
    }
    __syncthreads();

    const int ty = t >> 4, tx = t & 15;
    const int r0 = ty * 4, cj = tx * 8;

    {
        float acc[4][8] = {};
        for (int k = 0; k < NPG; ++k) {
            float a[4];
            #pragma unroll
            for (int r = 0; r < 4; ++r) a[r] = Bs[(i0 + r0 + r) * 132 + k];
            float4 q0 = *(const float4*)&Bs[k * 132 + cj];
            float4 q1 = *(const float4*)&Bs[k * 132 + cj + 4];
            float bb[8] = {q0.x, q0.y, q0.z, q0.w, q1.x, q1.y, q1.z, q1.w};
            #pragma unroll
            for (int r = 0; r < 4; ++r)
                #pragma unroll
                for (int c = 0; c < 8; ++c)
                    acc[r][c] = fmaf(a[r], bb[c], acc[r][c]);
        }
        #pragma unroll
        for (int r = 0; r < 4; ++r) {
            *(float4*)&A2s[(r0 + r) * 132 + cj]     = make_float4(acc[r][0], acc[r][1], acc[r][2], acc[r][3]);
            *(float4*)&A2s[(r0 + r) * 132 + cj + 4] = make_float4(acc[r][4], acc[r][5], acc[r][6], acc[r][7]);
        }
    }
    __syncthreads();

    for (int e = t; e < 64 * FIN; e += 256) {
        int i = e / FIN, d = e - (e / FIN) * FIN;
        float s = 0.f;
        for (int k = 0; k < NPG; ++k) s = fmaf(A2s[i * 132 + k], xg[k * FIN + d], s);
        p2f[(i0 + i) * 8 + d] = s;
        __hip_atomic_store(&Xp2[g * 1024 + (i0 + i) * 8 + d], s, __ATOMIC_RELAXED, AGENT);
    }
    gbar(cnt + g * 2 + 0, 2u);
    for (int e = t; e < 64 * FIN; e += 256) {
        int i = e / FIN, d = e - (e / FIN) * FIN;
        p2f[(i0p + i) * 8 + d] =
            __hip_atomic_load(&Xp2[g * 1024 + (i0p + i) * 8 + d], __ATOMIC_RELAXED, AGENT);
    }
    __syncthreads();
    for (int e = t; e < NPG * WID; e += 256) {
        int i = e >> 7, o = e & 127;
        float s = b1s[o];
        #pragma unroll
        for (int d = 0; d < FIN; ++d) s = fmaf(p2f[i * 8 + d], W1s[d * WID + o], s);
        Bs[i * 132 + o] = leaky(s);
    }
    __syncthreads();
    if (half == 0 && t < WID) {
        float sm = 0.f, mx = -BIG;
        for (int i = 0; i < NPG; ++i) { float v = Bs[i * 132 + t]; sm += v; mx = fmaxf(mx, v); }
        Zp[g * D2 + t]       = sm * (1.f / NPG);
        Zp[g * D2 + WID + t] = mx;
    }

    {
        float acc[4][8] = {};
        for (int k = 0; k < NPG; ++k) {
            float a[4];
            #pragma unroll
            for (int r = 0; r < 4; ++r) a[r] = A2s[(r0 + r) * 132 + k];
            float4 q0 = *(const float4*)&Bs[k * 132 + cj];
            float4 q1 = *(const float4*)&Bs[k * 132 + cj + 4];
            float bb[8] = {q0.x, q0.y, q0.z, q0.w, q1.x, q1.y, q1.z, q1.w};
            #pragma unroll
            for (int r = 0; r < 4; ++r)
                #pragma unroll
                for (int c = 0; c < 8; ++c)
                    acc[r][c] = fmaf(a[r], bb[c], acc[r][c]);
        }
        #pragma unroll
        for (int r = 0; r < 4; ++r) {
            *(float4*)&Ps[(r0 + r) * 132 + cj]     = make_float4(acc[r][0], acc[r][1], acc[r][2], acc[r][3]);
            *(float4*)&Ps[(r0 + r) * 132 + cj + 4] = make_float4(acc[r][4], acc[r][5], acc[r][6], acc[r][7]);
        }
        __syncthreads();
        float o2[4][8] = {};
        const float* W2 = Wc;
        for (int d = 0; d < NPG; ++d) {
            float a[4];
            #pragma unroll
            for (int r = 0; r < 4; ++r) a[r] = Ps[(r0 + r) * 132 + d];
            float4 w0 = *(const float4*)&W2[d * WID + cj];
            float4 w1 = *(const float4*)&W2[d * WID + cj + 4];
            float bb[8] = {w0.x, w0.y, w0.z, w0.w, w1.x, w1.y, w1.z, w1.w};
            #pragma unroll
            for (int r = 0; r < 4; ++r)
                #pragma unroll
                for (int c = 0; c < 8; ++c)
                    o2[r][c] = fmaf(a[r], bb[c], o2[r][c]);
        }
        #pragma unroll
        for (int r = 0; r < 4; ++r)
            #pragma unroll
            for (int c = 0; c < 8; ++c)
                Bs[(i0 + r0 + r) * 132 + cj + c] = leaky(o2[r][c] + bc[cj + c]);
    }
    __syncthreads();
    for (int e = t; e < 64 * WID; e += 256) {
        int i = i0 + (e >> 7), o = e & 127;
        __hip_atomic_store(&Xh2[(size_t)g * 16384 + i * WID + o], Bs[i * 132 + o],
                           __ATOMIC_RELAXED, AGENT);
    }
    gbar(cnt + g * 2 + 1, 2u);
    for (int e = t; e < 64 * WID; e += 256) {
        int i = i0p + (e >> 7), o = e & 127;
        Bs[i * 132 + o] =
            __hip_atomic_load(&Xh2[(size_t)g * 16384 + i * WID + o], __ATOMIC_RELAXED, AGENT);
    }
    __syncthreads();
    if (half == 0 && t < WID) {
        float sm = 0.f, mx = -BIG;
        for (int i = 0; i < NPG; ++i) { float v = Bs[i * 132 + t]; sm += v; mx = fmaxf(mx, v); }
        Zp[g * D2 + 256 + t]       = sm * (1.f / NPG);
        Zp[g * D2 + 256 + WID + t] = mx;
    }

    {
        float acc[4][8] = {};
        for (int k = 0; k < NPG; ++k) {
            float a[4];
            #pragma unroll
            for (int r = 0; r < 4; ++r) a[r] = A2s[(r0 + r) * 132 + k];
            float4 q0 = *(const float4*)&Bs[k * 132 + cj];
            float4 q1 = *(const float4*)&Bs[k * 132 + cj + 4];
            float bb[8] = {q0.x, q0.y, q0.z, q0.w, q1.x, q1.y, q1.z, q1.w};
            #pragma unroll
            for (int r = 0; r < 4; ++r)
                #pragma unroll
                for (int c = 0; c < 8; ++c)
                    acc[r][c] = fmaf(a[r], bb[c], acc[r][c]);
        }
        __syncthreads();
        #pragma unroll
        for (int r = 0; r < 4; ++r) {
            *(float4*)&Ps[(r0 + r) * 132 + cj]     = make_float4(acc[r][0], acc[r][1], acc[r][2], acc[r][3]);
            *(float4*)&Ps[(r0 + r) * 132 + cj + 4] = make_float4(acc[r][4], acc[r][5], acc[r][6], acc[r][7]);
        }
        __syncthreads();
        float o3[4][8] = {};
        const float* W3 = Wc + WID * WID;
        const float* b3 = bc + WID;
        for (int d = 0; d < NPG; ++d) {
            float a[4];
            #pragma unroll
            for (int r = 0; r < 4; ++r) a[r] = Ps[(r0 + r) * 132 + d];
            float4 w0 = *(const float4*)&W3[d * WID + cj];
            float4 w1 = *(const float4*)&W3[d * WID + cj + 4];
            float bb[8] = {w0.x, w0.y, w0.z, w0.w, w1.x, w1.y, w1.z, w1.w};
            #pragma unroll
            for (int r = 0; r < 4; ++r)
                #pragma unroll
                for (int c = 0; c < 8; ++c)
                    o3[r][c] = fmaf(a[r], bb[c], o3[r][c]);
        }
        __syncthreads();
        #pragma unroll
        for (int r = 0; r < 4; ++r)
            #pragma unroll
            for (int c = 0; c < 8; ++c)
                Ps[(r0 + r) * 132 + cj + c] = leaky(o3[r][c] + b3[cj + c]);
    }
    __syncthreads();
    if (t < WID) {
        float sm = 0.f, mx = -BIG;
        for (int i = 0; i < 64; ++i) { float v = Ps[i * 132 + t]; sm += v; mx = fmaxf(mx, v); }
        Zp3[(size_t)(g * 2 + half) * 256 + t]       = sm;
        Zp3[(size_t)(g * 2 + half) * 256 + 128 + t] = mx;
    }
}

// ---------------- K3: tail. grid 96 (8 cols each), block 256 ----------------
// All 5 layers' W panels staged to LDS up front (120 KB), fetched with 10-deep
// in-flight float4 batches. Per layer: wave w = k-slice 192, W via ds_read_b128
// broadcast (L2-invalidation-immune), z coalesced, 4-way split-K LDS reduce.
__device__ __forceinline__ float bn_val(const float* Zp, const float* Zp3, int c, int r)
{
    if (c < 512) return Zp[r * D2 + c];
    int o = c - 512;
    if (o < 128)
        return (Zp3[(size_t)(r * 2) * 256 + o] + Zp3[(size_t)(r * 2 + 1) * 256 + o]) * (1.f / NPG);
    o -= 128;
    return fmaxf(Zp3[(size_t)(r * 2) * 256 + 128 + o], Zp3[(size_t)(r * 2 + 1) * 256 + 128 + o]);
}

__global__ __launch_bounds__(256, 1) void k_tail(
    const float* __restrict__ Zp, const float* __restrict__ Zp3,
    const float* __restrict__ bng, const float* __restrict__ bnb,
    const float* __restrict__ linW, const float* __restrict__ linb,
    const float* __restrict__ outW, const float* __restrict__ outb,
    float* __restrict__ ZT0, float* __restrict__ ZT1,
    float* __restrict__ out, unsigned* __restrict__ cnt)
{
    const int b = blockIdx.x;        // 96 blocks x 8 cols
    const int t = threadIdx.x;
    const int c0 = b * 8;
    __shared__ float WL[5 * D2 * 8]; // 120 KB: all 5 layers' W panels
    __shared__ float sc1[D2];        // BN scratch / head outW (3 KB)
    __shared__ float red[4 * 8 * 64];// split-K partials (8 KB)

    // ---- issue W panel fetch FIRST (3 batches x 10 in-flight f4/thread) ----
    {
        #pragma unroll
        for (int batch = 0; batch < 3; ++batch) {
            f4 buf[10];
            #pragma unroll
            for (int j = 0; j < 10; ++j) {
                int e4 = t + (batch * 10 + j) * 256;          // 0..7679
                int l = e4 / 1536, rem = e4 - l * 1536;
                int k = rem >> 1, c4 = (rem & 1) * 4;
                buf[j] = *(const f4*)&linW[(size_t)l * D2 * D2 + (size_t)k * D2 + c0 + c4];
            }
            #pragma unroll
            for (int j = 0; j < 10; ++j) {
                int e4 = t + (batch * 10 + j) * 256;
                *(f4*)&WL[e4 * 4] = buf[j];
            }
        }
    }

    // ---- BN + transpose -> ZT0 (16 cols handled by pairs of blocks? no: 8 cols/block) ----
    {
        int sub = t >> 5, rq = t & 31;    // 8 cols x 32 threads, 2 rows each
        int c = c0 + sub;
        float s = 0.f, s2 = 0.f;
        #pragma unroll
        for (int rr = 0; rr < 2; ++rr) {
            float v = bn_val(Zp, Zp3, c, rq * 2 + rr);
            s += v; s2 = fmaf(v, v, s2);
        }
        sc1[sub * 32 + rq] = s;
        sc1[256 + sub * 32 + rq] = s2;
        __syncthreads();
        if (t < 8) {
            float ss = 0.f, qq = 0.f;
            #pragma unroll
            for (int q = 0; q < 32; ++q) { ss += sc1[t * 32 + q]; qq += sc1[256 + t * 32 + q]; }
            float m   = ss * (1.f / NG);
            float var = qq * (1.f / NG) - m * m;
            sc1[512 + t] = m;
            sc1[520 + t] = rsqrtf(var + BNEPS) * bng[c0 + t];
            sc1[528 + t] = bnb[c0 + t];
        }
        __syncthreads();
        float m = sc1[512 + sub], sc = sc1[520 + sub], bt = sc1[528 + sub];
        #pragma unroll
        for (int rr = 0; rr < 2; ++rr) {
            int rx = rq * 2 + rr;
            float v = bn_val(Zp, Zp3, c, rx);
            ZT0[c * NG + rx] = (v - m) * sc + bt;
        }
    }
    gbar(cnt + 128, 96u);   // also drains the W-panel loads' lgkmcnt via syncthreads

    // ---- 5 MLP layers: wave = k-slice, W broadcast from LDS ----
    const int w = __builtin_amdgcn_readfirstlane(t >> 6);
    const int r = t & 63;
    for (int l = 0; l < 5; ++l) {
        const float* zin  = (l & 1) ? ZT1 : ZT0;
        float*       zout = (l & 1) ? ZT0 : ZT1;
        const float* WLl = &WL[l * D2 * 8];
        const int k0 = w * 192;
        float acc[8];
        #pragma unroll
        for (int c = 0; c < 8; ++c) acc[c] = 0.f;
        for (int kk = 0; kk < 192; kk += 8) {
            float zv[8];
            #pragma unroll
            for (int u = 0; u < 8; ++u)
                zv[u] = zin[(k0 + kk + u) * NG + r];
            #pragma unroll
            for (int u = 0; u < 8; ++u) {
                f4 w0 = *(const f4*)&WLl[(k0 + kk + u) * 8];      // broadcast ds_read_b128
                f4 w1 = *(const f4*)&WLl[(k0 + kk + u) * 8 + 4];
                acc[0] = fmaf(zv[u], w0.x, acc[0]); acc[1] = fmaf(zv[u], w0.y, acc[1]);
                acc[2] = fmaf(zv[u], w0.z, acc[2]); acc[3] = fmaf(zv[u], w0.w, acc[3]);
                acc[4] = fmaf(zv[u], w1.x, acc[4]); acc[5] = fmaf(zv[u], w1.y, acc[5]);
                acc[6] = fmaf(zv[u], w1.z, acc[6]); acc[7] = fmaf(zv[u], w1.w, acc[7]);
            }
        }
        __syncthreads();                  // red free
        #pragma unroll
        for (int c = 0; c < 8; ++c)
            red[(w * 8 + c) * 64 + r] = acc[c];
        __syncthreads();
        {                                  // reduce 4 partials; thread -> (col, 2 rows)
            int c = t >> 5, rb = (t & 31) * 2;
            float bv = linb[l * D2 + c0 + c];
            f2 v;
            #pragma unroll
            for (int j = 0; j < 2; ++j) {
                int rr = rb + j;
                float s = red[(0 * 8 + c) * 64 + rr] + red[(1 * 8 + c) * 64 + rr]
                        + red[(2 * 8 + c) * 64 + rr] + red[(3 * 8 + c) * 64 + rr];
                v[j] = leaky(s + bv);
            }
            *(f2*)&zout[(c0 + c) * NG + rb] = v;
        }
        gbar(cnt + 129 + l, 96u);
    }

    // ---- head (block 0) ----
    if (b == 0) {
        for (int e = t; e < D2; e += 256) sc1[e] = outW[e];
        __syncthreads();
        int kq = t >> 6, rr = t & 63;
        const float* zf = ZT1;            // after 5 layers
        float s = 0.f;
        #pragma unroll 16
        for (int k = kq * 192; k < kq * 192 + 192; ++k)
            s = fmaf(zf[k * NG + rr], sc1[k], s);
        red[kq * 64 + rr] = s;
        __syncthreads();
        if (t < 64)
            out[t] = red[t] + red[64 + t] + red[128 + t] + red[192 + t] + outb[0];
    }
}

extern "C" void kernel_launch(void* const* d_in, const int* in_sizes, int n_in,
                              void* d_out, int out_size, void* d_ws, size_t ws_size,
                              hipStream_t stream)
{
    (void)in_sizes; (void)n_in; (void)out_size; (void)ws_size;
    const float* x       = (const float*)d_in[0];
    // d_in[1] = batch: fixed structure (i/128), unused
    const float* conv1_W = (const float*)d_in[2];
    const float* conv1_b = (const float*)d_in[3];
    const float* convs_W = (const float*)d_in[4];
    const float* convs_b = (const float*)d_in[5];
    const float* bn_g    = (const float*)d_in[6];
    const float* bn_b    = (const float*)d_in[7];
    const float* lin_W   = (const float*)d_in[8];
    const float* lin_b   = (const float*)d_in[9];
    const float* out_W   = (const float*)d_in[10];
    const float* out_b   = (const float*)d_in[11];

    float* f = (float*)d_ws;
    float* A   = f;                      // 1M floats
    float* Xh2 = f + (1 << 20);          // 1M
    float* Xp2 = f + (2 << 20);          // 65536
    float* Zp  = Xp2 + 65536;            // 49152
    float* Zp3 = Zp + NG * D2;           // 32768
    float* ZT0 = Zp3 + 32768;            // 49152
    float* ZT1 = ZT0 + NG * D2;          // 49152
    unsigned* cnt = (unsigned*)(f + (4 << 20));   // 16 MB offset; counters
    float* outp = (float*)d_out;

    hipMemsetAsync(cnt, 0, 1024, stream);
    k_knn  <<<dim3(512), dim3(256), 0, stream>>>(x, A);
    k_graph<<<dim3(128), dim3(256), 0, stream>>>(A, x, conv1_W, conv1_b, convs_W, convs_b,
                                                 Xp2, Xh2, Zp, Zp3, cnt);
    k_tail <<<dim3(96),  dim3(256), 0, stream>>>(Zp, Zp3, bn_g, bn_b, lin_W, lin_b,
                                                 out_W, out_b, ZT0, ZT1, outp, cnt);
}